// Round 8
// baseline (439.911 us; speedup 1.0000x reference)
//
#include <hip/hip_runtime.h>
#include <stdint.h>

#define NCOLS 8192
#define BS    256
#define NB    16
#define NTO   128                 // cols per wg (512B runs)
#define KSTEP 64                  // K rows per step
#define NSTEPS 4                  // BS / KSTEP
#define GX    (NCOLS / NTO)       // 64 -> grid 64x16 = 1024 wgs, 2/CU resident
#define NCW   8                   // consumer waves (M=32 each)
#define NPW   4                   // producer waves (16 K-rows each per step)

typedef float    f32x4  __attribute__((ext_vector_type(4)));
typedef short    bf16x8 __attribute__((ext_vector_type(8)));
typedef unsigned u32x4  __attribute__((ext_vector_type(4)));

// RNE-pack two fp32 into one dword of two bf16 (lo = first arg)
__device__ __forceinline__ unsigned pack2(float lo, float hi) {
  unsigned a = __builtin_bit_cast(unsigned, lo);
  unsigned b = __builtin_bit_cast(unsigned, hi);
  a += 0x7FFFu + ((a >> 16) & 1u);
  b += 0x7FFFu + ((b >> 16) & 1u);
  return (a >> 16) | (b & 0xFFFF0000u);
}

// Convert W (16x256x256 fp32) -> bf16 in ws. 8 elems/thread.
__global__ __launch_bounds__(256) void wcvt_kernel(const float* __restrict__ Wf,
                                                   unsigned* __restrict__ Wb) {
  int i = blockIdx.x * 256 + threadIdx.x;
  f32x4 a = ((const f32x4*)Wf)[2 * i];
  f32x4 c = ((const f32x4*)Wf)[2 * i + 1];
  u32x4 o;
  o.x = pack2(a.x, a.y); o.y = pack2(a.z, a.w);
  o.z = pack2(c.x, c.y); o.w = pack2(c.z, c.w);
  ((u32x4*)Wb)[i] = o;
}

// K-split producer/consumer wg: block b x NTO=128 cols x full K, 4 K-steps of 64.
// Reads and writes both move in 512B contiguous runs per row (DRAM page
// locality). 8 consumer waves: W band in regs (AGPR-parked, pinned), acc[2][8]
// across all K-steps, single 512B-run store epilogue. 4 producer waves:
// X fp32 -> regs -> pack2 -> swizzled bf16 LDS, depth-2 prefetch.
// One raw s_barrier per K-step; no vmcnt(0) in the loop on any path.
template<bool USE_WS>
__global__ __launch_bounds__(768, 6)
void bg_kernel(const float* __restrict__ X, const float* __restrict__ Wf,
               const unsigned short* __restrict__ Wb, float* __restrict__ out) {
  __shared__ unsigned xb[2][NTO * 32];  // [n][kd^swz] dwords; 16 KiB per buffer

  const int b    = blockIdx.y;
  const int c0   = blockIdx.x * NTO;
  const int tid  = threadIdx.x;
  const int wid  = tid >> 6;
  const int lane = tid & 63;

  if (wid < NCW) {
    // ================= CONSUMER =================
    const int cw   = wid;          // M-band cw*32..+31
    const int ln16 = lane & 15;
    const int quad = lane >> 4;

    // W band -> wfr[8][2] (64 regs), loaded once, pinned against remat.
    bf16x8 wfr[8][2];
    {
      const size_t wb0 = ((size_t)(b * BS + cw * 32 + ln16)) * BS + quad * 8;
      if (USE_WS) {
#pragma unroll
        for (int kg = 0; kg < 8; ++kg)
#pragma unroll
          for (int mt = 0; mt < 2; ++mt)
            wfr[kg][mt] = *(const bf16x8*)(Wb + wb0 + (size_t)(mt * 16) * BS + kg * 32);
      } else {
#pragma unroll
        for (int kg = 0; kg < 8; ++kg)
#pragma unroll
          for (int mt = 0; mt < 2; ++mt) {
            const size_t off = wb0 + (size_t)(mt * 16) * BS + kg * 32;
            f32x4 w0 = *(const f32x4*)(Wf + off);
            f32x4 w1 = *(const f32x4*)(Wf + off + 4);
            union { unsigned u[4]; bf16x8 v; } cv;
            cv.u[0] = pack2(w0.x, w0.y); cv.u[1] = pack2(w0.z, w0.w);
            cv.u[2] = pack2(w1.x, w1.y); cv.u[3] = pack2(w1.z, w1.w);
            wfr[kg][mt] = cv.v;
          }
      }
#pragma unroll
      for (int kg = 0; kg < 8; ++kg)
#pragma unroll
        for (int mt = 0; mt < 2; ++mt)
          __asm__ volatile("" : "+v"(wfr[kg][mt]));  // opaque: no remat
    }

    f32x4 acc[2][8] = {};  // M=32 x N=128 per wave, held across all K-steps

    __builtin_amdgcn_s_barrier();  // K-step 0 published by producers
    __builtin_amdgcn_sched_barrier(0);

    // fully unrolled so wfr[s*2+ksl] is compile-time indexed (no scratch)
#pragma unroll
    for (int s = 0; s < NSTEPS; ++s) {
      const unsigned* buf = &xb[s & 1][0];
      bf16x8 bfr[2][8];
#pragma unroll
      for (int ksl = 0; ksl < 2; ++ksl)
#pragma unroll
        for (int nt = 0; nt < 8; ++nt) {
          const int n = nt * 16 + ln16;
          const int f = (n ^ (n >> 2)) & 7;
          bfr[ksl][nt] = *(const bf16x8*)(&buf[n * 32 + ((ksl * 16 + quad * 4) ^ (f << 2))]);
        }
#pragma unroll
      for (int ksl = 0; ksl < 2; ++ksl)
#pragma unroll
        for (int mt = 0; mt < 2; ++mt)
#pragma unroll
          for (int nt = 0; nt < 8; ++nt)
            acc[mt][nt] = __builtin_amdgcn_mfma_f32_16x16x32_bf16(
                wfr[s * 2 + ksl][mt], bfr[ksl][nt], acc[mt][nt], 0, 0, 0);
      __builtin_amdgcn_s_barrier();
      __builtin_amdgcn_sched_barrier(0);
    }

    // ---- epilogue: direct stores, 512B contiguous per output row
#pragma unroll
    for (int mt = 0; mt < 2; ++mt)
#pragma unroll
      for (int r = 0; r < 4; ++r) {
        float* orow = out + (size_t)(b * BS + cw * 32 + mt * 16 + quad * 4 + r) * NCOLS
                          + c0 + ln16;
#pragma unroll
        for (int nt = 0; nt < 8; ++nt)
          orow[nt * 16] = acc[mt][nt][r];
      }
  } else {
    // ================= PRODUCER =================
    const int pw   = wid - NCW;    // stages K-rows pw*16..+15 of each step
    const int half = lane >> 5;    // 0/1
    const int lc5  = lane & 31;    // col group (4 floats)

    f32x4 st[8];  // one K-step's 8 rows x 16B per lane; never held across MFMA
    auto load_step = [&](int s) {
      const float* base = X + (size_t)(b * BS + s * KSTEP + pw * 16 + half * 8) * NCOLS
                            + c0 + lc5 * 4;
#pragma unroll
      for (int v = 0; v < 8; ++v)
        st[v] = *(const f32x4*)(base + (size_t)v * NCOLS);
    };
    // kd = pw*8 + half*4 + w2 (4-aligned base), XOR f<<2 keeps b128 contiguity
    auto pack_step = [&](unsigned* buf) {
      const int kd4 = pw * 8 + half * 4;
#pragma unroll
      for (int j = 0; j < 4; ++j) {
        const int n = lc5 * 4 + j;
        const int f = (n ^ (n >> 2)) & 7;
        u32x4 o;
#pragma unroll
        for (int w2 = 0; w2 < 4; ++w2)
          o[w2] = pack2(st[2 * w2][j], st[2 * w2 + 1][j]);
        *(u32x4*)(&buf[n * 32 + (kd4 ^ (f << 2))]) = o;
      }
    };

    // prologue: step0 -> xb[0]; step1 loads in flight; publish
    load_step(0);
    __builtin_amdgcn_sched_barrier(0);
    pack_step(&xb[0][0]);          // counted vmcnt wait on st only
    load_step(1);
    __builtin_amdgcn_sched_barrier(0);
    __asm__ volatile("s_waitcnt lgkmcnt(0)" ::: "memory");
    __builtin_amdgcn_s_barrier();

#pragma unroll 1
    for (int s = 0; s < NSTEPS; ++s) {
      if (s + 1 < NSTEPS) {
        pack_step(&xb[(s + 1) & 1][0]);   // st = step s+1, loaded a period ago
        if (s + 2 < NSTEPS) load_step(s + 2);
        __builtin_amdgcn_sched_barrier(0);
        __asm__ volatile("s_waitcnt lgkmcnt(0)" ::: "memory");
      }
      __builtin_amdgcn_s_barrier();
    }
  }
}

extern "C" void kernel_launch(void* const* d_in, const int* in_sizes, int n_in,
                              void* d_out, int out_size, void* d_ws, size_t ws_size,
                              hipStream_t stream) {
  const float* X  = (const float*)d_in[0];
  const float* Wf = (const float*)d_in[1];
  float* out      = (float*)d_out;
  dim3 grid(GX, NB);
  const size_t wneed = (size_t)NB * BS * BS * sizeof(unsigned short);
  if (ws_size >= wneed) {
    unsigned* Wb = (unsigned*)d_ws;
    wcvt_kernel<<<dim3((NB * BS * BS) / (256 * 8)), 256, 0, stream>>>(Wf, Wb);
    bg_kernel<true><<<grid, 768, 0, stream>>>(X, Wf, (const unsigned short*)Wb, out);
  } else {
    bg_kernel<false><<<grid, 768, 0, stream>>>(X, Wf, nullptr, out);
  }
}

// Round 9
// 235.795 us; speedup vs baseline: 1.8656x; 1.8656x over previous
//
#include <hip/hip_runtime.h>
#include <stdint.h>

#define NCOLS 8192
#define BS    256
#define NB    16
#define NTO   128                 // cols per wg (512B runs on X reads and out writes)
#define KSTEP 64                  // K rows per step
#define NSTEPS 4                  // BS / KSTEP
#define GX    (NCOLS / NTO)       // 64 -> grid 64x16 = 1024 wgs
#define NCW   8                   // consumer waves (M=32 each)
#define NPW   4                   // producer waves (16 K-rows each per step)

typedef float    f32x4  __attribute__((ext_vector_type(4)));
typedef short    bf16x8 __attribute__((ext_vector_type(8)));
typedef unsigned u32x4  __attribute__((ext_vector_type(4)));

// RNE-pack two fp32 into one dword of two bf16 (lo = first arg)
__device__ __forceinline__ unsigned pack2(float lo, float hi) {
  unsigned a = __builtin_bit_cast(unsigned, lo);
  unsigned b = __builtin_bit_cast(unsigned, hi);
  a += 0x7FFFu + ((a >> 16) & 1u);
  b += 0x7FFFu + ((b >> 16) & 1u);
  return (a >> 16) | (b & 0xFFFF0000u);
}

// Convert W (16x256x256 fp32) -> bf16 in ws. 8 elems/thread.
__global__ __launch_bounds__(256) void wcvt_kernel(const float* __restrict__ Wf,
                                                   unsigned* __restrict__ Wb) {
  int i = blockIdx.x * 256 + threadIdx.x;
  f32x4 a = ((const f32x4*)Wf)[2 * i];
  f32x4 c = ((const f32x4*)Wf)[2 * i + 1];
  u32x4 o;
  o.x = pack2(a.x, a.y); o.y = pack2(a.z, a.w);
  o.z = pack2(c.x, c.y); o.w = pack2(c.z, c.w);
  ((u32x4*)Wb)[i] = o;
}

// K-split producer/consumer wg: block b x NTO=128 cols x full K, 4 K-steps of 64.
// Both HBM streams move in 512B contiguous runs per row. 8 consumer waves:
// acc[2][8] across K-steps; W frags per-step double-buffered from L2-hot Wb
// (32 regs, prefetched one step ahead); bfr single-buffered. 4 producer waves:
// X fp32 -> regs -> pack2 -> swizzled bf16 LDS (conflict-free, r8-proven),
// depth-2 prefetch. One raw s_barrier per step; no vmcnt(0) in the loop.
// Register budget engineered for __launch_bounds__(768,3)'s 170 cap (~150 used).
template<bool USE_WS>
__global__ __launch_bounds__(768, 3)
void bg_kernel(const float* __restrict__ X, const float* __restrict__ Wf,
               const unsigned short* __restrict__ Wb, float* __restrict__ out) {
  __shared__ unsigned xb[2][NTO * 32];  // [n][kd^swz] dwords; 16 KiB per buffer

  const int b    = blockIdx.y;
  const int c0   = blockIdx.x * NTO;
  const int tid  = threadIdx.x;
  const int wid  = tid >> 6;
  const int lane = tid & 63;

  if (wid < NCW) {
    // ================= CONSUMER =================
    const int cw   = wid;          // M-band cw*32..+31
    const int ln16 = lane & 15;
    const int quad = lane >> 4;
    const size_t wb0 = ((size_t)(b * BS + cw * 32 + ln16)) * BS + quad * 8;

    auto loadW = [&](int kg, int mt) -> bf16x8 {
      const size_t off = wb0 + (size_t)(mt * 16) * BS + kg * 32;
      if (USE_WS) {
        return *(const bf16x8*)(Wb + off);
      } else {
        f32x4 w0 = *(const f32x4*)(Wf + off);
        f32x4 w1 = *(const f32x4*)(Wf + off + 4);
        union { unsigned u[4]; bf16x8 v; } cv;
        cv.u[0] = pack2(w0.x, w0.y); cv.u[1] = pack2(w0.z, w0.w);
        cv.u[2] = pack2(w1.x, w1.y); cv.u[3] = pack2(w1.z, w1.w);
        return cv.v;
      }
    };

    f32x4  acc[2][8] = {};      // 64 VGPR: M=32 x N=128 per wave
    bf16x8 wfr[2][2][2];        // 32 VGPR: [stepbuf][ksl][mt], per-step W frags

#pragma unroll
    for (int ksl = 0; ksl < 2; ++ksl)
#pragma unroll
      for (int mt = 0; mt < 2; ++mt)
        wfr[0][ksl][mt] = loadW(ksl, mt);

    __builtin_amdgcn_s_barrier();  // K-step 0 published by producers

#pragma unroll
    for (int s = 0; s < NSTEPS; ++s) {     // full unroll: all reg indexing static
      const unsigned* buf = &xb[s & 1][0];
      if (s + 1 < NSTEPS) {                // prefetch next step's W under compute
#pragma unroll
        for (int ksl = 0; ksl < 2; ++ksl)
#pragma unroll
          for (int mt = 0; mt < 2; ++mt)
            wfr[(s + 1) & 1][ksl][mt] = loadW((s + 1) * 2 + ksl, mt);
      }
#pragma unroll
      for (int ksl = 0; ksl < 2; ++ksl) {
        bf16x8 bfr[8];                     // 32 VGPR, single-buffered
#pragma unroll
        for (int nt = 0; nt < 8; ++nt) {
          const int n = nt * 16 + ln16;
          const int f = (n ^ (n >> 2)) & 7;
          bfr[nt] = *(const bf16x8*)(&buf[n * 32 + ((ksl * 16 + quad * 4) ^ (f << 2))]);
        }
#pragma unroll
        for (int mt = 0; mt < 2; ++mt)
#pragma unroll
          for (int nt = 0; nt < 8; ++nt)
            acc[mt][nt] = __builtin_amdgcn_mfma_f32_16x16x32_bf16(
                wfr[s & 1][ksl][mt], bfr[nt], acc[mt][nt], 0, 0, 0);
      }
      __builtin_amdgcn_s_barrier();
    }

    // ---- epilogue: direct stores, 512B contiguous per output row
#pragma unroll
    for (int mt = 0; mt < 2; ++mt)
#pragma unroll
      for (int r = 0; r < 4; ++r) {
        float* orow = out + (size_t)(b * BS + cw * 32 + mt * 16 + quad * 4 + r) * NCOLS
                          + c0 + ln16;
#pragma unroll
        for (int nt = 0; nt < 8; ++nt)
          orow[nt * 16] = acc[mt][nt][r];
      }
  } else {
    // ================= PRODUCER (r8-proven, conflict-free) =================
    const int pw   = wid - NCW;    // stages K-rows pw*16..+15 of each step
    const int half = lane >> 5;    // 0/1
    const int lc5  = lane & 31;    // col group (4 floats): 32 lanes x 4 = 128 cols

    f32x4 st[8];  // one K-step's 8 rows x 16B per lane; never held across MFMA
    auto load_step = [&](int s) {
      const float* base = X + (size_t)(b * BS + s * KSTEP + pw * 16 + half * 8) * NCOLS
                            + c0 + lc5 * 4;
#pragma unroll
      for (int v = 0; v < 8; ++v)
        st[v] = *(const f32x4*)(base + (size_t)v * NCOLS);
    };
    // kd4 = pw*8 + half*4 is 4-aligned; f<<2 only touches bits>=2 -> b128 writes
    auto pack_step = [&](unsigned* buf) {
      const int kd4 = pw * 8 + half * 4;
#pragma unroll
      for (int j = 0; j < 4; ++j) {
        const int n = lc5 * 4 + j;
        const int f = (n ^ (n >> 2)) & 7;
        u32x4 o;
#pragma unroll
        for (int w2 = 0; w2 < 4; ++w2)
          o[w2] = pack2(st[2 * w2][j], st[2 * w2 + 1][j]);
        *(u32x4*)(&buf[n * 32 + (kd4 ^ (f << 2))]) = o;
      }
    };

    // prologue: step0 -> xb[0]; step1 loads in flight; publish
    load_step(0);
    __builtin_amdgcn_sched_barrier(0);
    pack_step(&xb[0][0]);          // counted vmcnt wait on st only
    load_step(1);
    __builtin_amdgcn_sched_barrier(0);
    __asm__ volatile("s_waitcnt lgkmcnt(0)" ::: "memory");
    __builtin_amdgcn_s_barrier();

#pragma unroll 1
    for (int s = 0; s < NSTEPS; ++s) {
      if (s + 1 < NSTEPS) {
        pack_step(&xb[(s + 1) & 1][0]);   // st = step s+1, loaded a period ago
        if (s + 2 < NSTEPS) load_step(s + 2);
        __builtin_amdgcn_sched_barrier(0);
        __asm__ volatile("s_waitcnt lgkmcnt(0)" ::: "memory");
      }
      __builtin_amdgcn_s_barrier();
    }
  }
}

extern "C" void kernel_launch(void* const* d_in, const int* in_sizes, int n_in,
                              void* d_out, int out_size, void* d_ws, size_t ws_size,
                              hipStream_t stream) {
  const float* X  = (const float*)d_in[0];
  const float* Wf = (const float*)d_in[1];
  float* out      = (float*)d_out;
  dim3 grid(GX, NB);
  const size_t wneed = (size_t)NB * BS * BS * sizeof(unsigned short);
  if (ws_size >= wneed) {
    unsigned* Wb = (unsigned*)d_ws;
    wcvt_kernel<<<dim3((NB * BS * BS) / (256 * 8)), 256, 0, stream>>>(Wf, Wb);
    bg_kernel<true><<<grid, 768, 0, stream>>>(X, Wf, (const unsigned short*)Wb, out);
  } else {
    bg_kernel<false><<<grid, 768, 0, stream>>>(X, Wf, nullptr, out);
  }
}